// Round 1
// baseline (120.617 us; speedup 1.0000x reference)
//
#include <hip/hip_runtime.h>
#include <hip/hip_bf16.h>

#define NH 4
#define HD 32
#define PAD 3
#define HW 56
#define NPIX (8*HW*HW)          // 25088 pixels
#define SCALE 0.17677669529663687f

// ---------------- workspace layout (bytes) ----------------
// qs   : f32  [8][4][56][56][32]   12,845,056 B
// kbuf : bf16 [8][4][56][56][32]    6,422,528 B
// vbuf : bf16 [8][4][56][56][32]    6,422,528 B
// attn : f32  [25088][128]         12,845,056 B
#define QS_OFF   0
#define K_OFF    12845056
#define V_OFF    (K_OFF + 6422528)
#define AT_OFF   (V_OFF + 6422528)

__device__ __forceinline__ float blo(unsigned u) { return __uint_as_float(u << 16); }
__device__ __forceinline__ float bhi(unsigned u) { return __uint_as_float(u & 0xffff0000u); }

__device__ __forceinline__ float dot8(const float* q8, uint4 k) {
    float s;
    s  = q8[0] * blo(k.x); s = fmaf(q8[1], bhi(k.x), s);
    s  = fmaf(q8[2], blo(k.y), s); s = fmaf(q8[3], bhi(k.y), s);
    s  = fmaf(q8[4], blo(k.z), s); s = fmaf(q8[5], bhi(k.z), s);
    s  = fmaf(q8[6], blo(k.w), s); s = fmaf(q8[7], bhi(k.w), s);
    return s;
}
__device__ __forceinline__ void axpy8(float* a8, float e, uint4 v) {
    a8[0] = fmaf(e, blo(v.x), a8[0]); a8[1] = fmaf(e, bhi(v.x), a8[1]);
    a8[2] = fmaf(e, blo(v.y), a8[2]); a8[3] = fmaf(e, bhi(v.y), a8[3]);
    a8[4] = fmaf(e, blo(v.z), a8[4]); a8[5] = fmaf(e, bhi(v.z), a8[5]);
    a8[6] = fmaf(e, blo(v.w), a8[6]); a8[7] = fmaf(e, bhi(v.w), a8[7]);
}

// ---------------------------------------------------------------------------
// fp32 GEMM: out[m][n] = sum_k A[m][k] * W[n][k] + bias[n]
// M = 25088 (pixels), K = 128.  BM = BN = 128, thread tile 8x8, 256 threads.
// SELQKV=1: N=384 (3 n-tiles), epilogue scatters q (scaled, f32) / k,v (bf16).
// SELQKV=0: N=128, epilogue writes f32 out rows.
// ---------------------------------------------------------------------------
template <int SELQKV>
__global__ __launch_bounds__(256, 2) void gemm_k(
    const float* __restrict__ A, const float* __restrict__ Wm,
    const float* __restrict__ bias,
    float* __restrict__ outq, __hip_bfloat16* __restrict__ outk,
    __hip_bfloat16* __restrict__ outv, float* __restrict__ outp)
{
    __shared__ float As[128 * 44];   // k-chunk=32 -> row stride 36.. use 44 pad (12 mod 32)
    __shared__ float Bs[128 * 44];

    const int tid = threadIdx.x;
    const int tx = tid & 15, ty = tid >> 4;
    const int m0 = blockIdx.x * 128;
    const int n0 = blockIdx.y * 128;

    float acc[8][8];
#pragma unroll
    for (int i = 0; i < 8; ++i)
#pragma unroll
        for (int j = 0; j < 8; ++j) acc[i][j] = 0.f;

    for (int kc = 0; kc < 4; ++kc) {   // 4 chunks of K=32
        __syncthreads();
#pragma unroll
        for (int it = 0; it < 4; ++it) {
            int idx = tid + it * 256;      // 0..1023
            int r   = idx >> 3;            // 0..127
            int k4  = idx & 7;             // 0..7
            float4 a = *(const float4*)(A  + (size_t)(m0 + r) * 128 + kc * 32 + k4 * 4);
            *(float4*)(&As[r * 44 + k4 * 4]) = a;
            float4 b = *(const float4*)(Wm + (size_t)(n0 + r) * 128 + kc * 32 + k4 * 4);
            *(float4*)(&Bs[r * 44 + k4 * 4]) = b;
        }
        __syncthreads();
#pragma unroll
        for (int k4 = 0; k4 < 8; ++k4) {
            float4 av[8], bv[8];
#pragma unroll
            for (int i = 0; i < 8; ++i) av[i] = *(const float4*)(&As[(ty + 16 * i) * 44 + k4 * 4]);
#pragma unroll
            for (int j = 0; j < 8; ++j) bv[j] = *(const float4*)(&Bs[(tx + 16 * j) * 44 + k4 * 4]);
#pragma unroll
            for (int i = 0; i < 8; ++i)
#pragma unroll
                for (int j = 0; j < 8; ++j) {
                    acc[i][j] = fmaf(av[i].x, bv[j].x, acc[i][j]);
                    acc[i][j] = fmaf(av[i].y, bv[j].y, acc[i][j]);
                    acc[i][j] = fmaf(av[i].z, bv[j].z, acc[i][j]);
                    acc[i][j] = fmaf(av[i].w, bv[j].w, acc[i][j]);
                }
        }
    }

    if constexpr (SELQKV) {
        const int sel = blockIdx.y;  // 0=q 1=k 2=v
#pragma unroll
        for (int i = 0; i < 8; ++i) {
            int m = m0 + ty + 16 * i;
            int b = m / 3136;
            int r = m - b * 3136;
            int y = r / 56;
            int x = r - y * 56;
#pragma unroll
            for (int j = 0; j < 8; ++j) {
                int nl = tx + 16 * j;                 // 0..127 within component
                float val = acc[i][j] + bias[n0 + nl];
                int h = nl >> 5, d = nl & 31;
                size_t oi = ((size_t)((b * NH + h) * 3136) + y * 56 + x) * 32 + d;
                if (sel == 0)      outq[oi] = val * SCALE;
                else if (sel == 1) outk[oi] = __float2bfloat16(val);
                else               outv[oi] = __float2bfloat16(val);
            }
        }
    } else {
#pragma unroll
        for (int i = 0; i < 8; ++i) {
            int m = m0 + ty + 16 * i;
#pragma unroll
            for (int j = 0; j < 8; ++j) {
                int nl = tx + 16 * j;
                outp[(size_t)m * 128 + nl] = acc[i][j] + bias[nl];
            }
        }
    }
}

// ---------------------------------------------------------------------------
// Neighborhood attention. Block = (b, head, 8x28 pixel tile), 256 threads
// (224 active). k/v halo 14x34 staged as bf16 in LDS, zero-filled OOB
// (matches the reference's zero-padding semantics: OOB score = rpb, v = 0).
// Single-pass softmax without max-subtraction (scores are O(0.1)).
// ---------------------------------------------------------------------------
__global__ __launch_bounds__(256, 2) void natt_k(
    const float* __restrict__ qs, const __hip_bfloat16* __restrict__ kb,
    const __hip_bfloat16* __restrict__ vb, const float* __restrict__ rpb,
    float* __restrict__ attn_out)
{
    __shared__ uint4 ks[4 * 476];   // [chunk c][pix]  pix = i*34+j, halo 14x34
    __shared__ uint4 vs[4 * 476];
    __shared__ float rp[49];

    const int tid = threadIdx.x;
    const int b = blockIdx.z, h = blockIdx.y;
    const int yt = blockIdx.x >> 1, xt = blockIdx.x & 1;
    const int y0 = yt * 8, x0 = xt * 28;
    const int bh = b * NH + h;

    if (tid < 49) rp[tid] = rpb[h * 49 + tid];

    const uint4* kg = (const uint4*)kb;  // 4 uint4 per pixel (32 bf16)
    const uint4* vg = (const uint4*)vb;
    for (int idx = tid; idx < 1904; idx += 256) {
        int pix = idx >> 2, c = idx & 3;
        int i = pix / 34;
        int j = pix - i * 34;
        int y = y0 + i - PAD;
        int x = x0 + j - PAD;
        uint4 z = make_uint4(0u, 0u, 0u, 0u);
        if ((unsigned)y < 56u && (unsigned)x < 56u) {
            int g = ((bh * 3136) + y * 56 + x) * 4 + c;
            ks[c * 476 + pix] = kg[g];
            vs[c * 476 + pix] = vg[g];
        } else {
            ks[c * 476 + pix] = z;
            vs[c * 476 + pix] = z;
        }
    }
    __syncthreads();

    if (tid >= 224) return;
    int py = tid / 28;
    int px = tid - py * 28;

    float q[32];
    {
        const float4* qgp = (const float4*)(qs + ((size_t)(bh * 3136) + (y0 + py) * 56 + (x0 + px)) * 32);
#pragma unroll
        for (int c = 0; c < 8; ++c) {
            float4 t = qgp[c];
            q[4 * c + 0] = t.x; q[4 * c + 1] = t.y; q[4 * c + 2] = t.z; q[4 * c + 3] = t.w;
        }
    }

    float acc[32];
#pragma unroll
    for (int d = 0; d < 32; ++d) acc[d] = 0.f;
    float l = 0.f;

    for (int dy = 0; dy < 7; ++dy) {
        int rowbase = (py + dy) * 34 + px;
#pragma unroll
        for (int dx = 0; dx < 7; ++dx) {
            int pix = rowbase + dx;
            float s = 0.f;
#pragma unroll
            for (int c = 0; c < 4; ++c) {
                uint4 kk = ks[c * 476 + pix];
                s += dot8(&q[c * 8], kk);
            }
            s += rp[dy * 7 + dx];
            float e = __expf(s);
            l += e;
#pragma unroll
            for (int c = 0; c < 4; ++c) {
                uint4 vv = vs[c * 476 + pix];
                axpy8(&acc[c * 8], e, vv);
            }
        }
    }

    float rl = 1.0f / l;
    float* op = attn_out + ((size_t)(b * 3136) + (y0 + py) * 56 + (x0 + px)) * 128 + h * 32;
#pragma unroll
    for (int c = 0; c < 8; ++c) {
        float4 o;
        o.x = acc[4 * c + 0] * rl; o.y = acc[4 * c + 1] * rl;
        o.z = acc[4 * c + 2] * rl; o.w = acc[4 * c + 3] * rl;
        *(float4*)(op + 4 * c) = o;
    }
}

extern "C" void kernel_launch(void* const* d_in, const int* in_sizes, int n_in,
                              void* d_out, int out_size, void* d_ws, size_t ws_size,
                              hipStream_t stream)
{
    const float* x     = (const float*)d_in[0];
    const float* Wqkv  = (const float*)d_in[1];
    const float* bqkv  = (const float*)d_in[2];
    const float* rpb   = (const float*)d_in[3];
    const float* Wproj = (const float*)d_in[4];
    const float* bproj = (const float*)d_in[5];
    float* out = (float*)d_out;

    char* ws = (char*)d_ws;
    float*           qsb  = (float*)(ws + QS_OFF);
    __hip_bfloat16*  kbuf = (__hip_bfloat16*)(ws + K_OFF);
    __hip_bfloat16*  vbuf = (__hip_bfloat16*)(ws + V_OFF);
    float*           attn = (float*)(ws + AT_OFF);

    // 1) QKV projection: 196 m-tiles x 3 n-tiles (q / k / v)
    gemm_k<1><<<dim3(196, 3), 256, 0, stream>>>(x, Wqkv, bqkv, qsb, kbuf, vbuf, nullptr);

    // 2) neighborhood attention: 14 tiles x 4 heads x 8 batch
    natt_k<<<dim3(14, NH, 8), 256, 0, stream>>>(qsb, kbuf, vbuf, rpb, attn);

    // 3) output projection
    gemm_k<0><<<dim3(196, 1), 256, 0, stream>>>(attn, Wproj, bproj, nullptr, nullptr, nullptr, out);
}

// Round 2
// 95.062 us; speedup vs baseline: 1.2688x; 1.2688x over previous
//
#include <hip/hip_runtime.h>
#include <hip/hip_bf16.h>

#define NH 4
#define HD 32
#define PAD 3
#define HW 56
#define NPIX (8*HW*HW)          // 25088 pixels
#define SCALE 0.17677669529663687f

// ---------------- workspace layout (bytes) ----------------
// qs   : f32  [8][4][56][56][32]   12,845,056 B
// kbuf : bf16 [8][4][56][56][32]    6,422,528 B
// vbuf : bf16 [8][4][56][56][32]    6,422,528 B
// attn : f32  [25088][128]         12,845,056 B
#define QS_OFF   0
#define K_OFF    12845056
#define V_OFF    (K_OFF + 6422528)
#define AT_OFF   (V_OFF + 6422528)

typedef __attribute__((ext_vector_type(8))) short short8v;
typedef __attribute__((ext_vector_type(4))) float f32x4;

__device__ __forceinline__ float blo(unsigned u) { return __uint_as_float(u << 16); }
__device__ __forceinline__ float bhi(unsigned u) { return __uint_as_float(u & 0xffff0000u); }

__device__ __forceinline__ unsigned short f2b(float x) {       // f32 -> bf16 bits, RNE
    unsigned u = __float_as_uint(x);
    unsigned r = (u + 0x7fffu + ((u >> 16) & 1u)) >> 16;
    return (unsigned short)r;
}
__device__ __forceinline__ float b2f(unsigned short s) { return __uint_as_float((unsigned)s << 16); }

__device__ __forceinline__ float dot8(const float* q8, uint4 k) {
    float s;
    s  = q8[0] * blo(k.x); s = fmaf(q8[1], bhi(k.x), s);
    s  = fmaf(q8[2], blo(k.y), s); s = fmaf(q8[3], bhi(k.y), s);
    s  = fmaf(q8[4], blo(k.z), s); s = fmaf(q8[5], bhi(k.z), s);
    s  = fmaf(q8[6], blo(k.w), s); s = fmaf(q8[7], bhi(k.w), s);
    return s;
}
__device__ __forceinline__ void axpy8(float* a8, float e, uint4 v) {
    a8[0] = fmaf(e, blo(v.x), a8[0]); a8[1] = fmaf(e, bhi(v.x), a8[1]);
    a8[2] = fmaf(e, blo(v.y), a8[2]); a8[3] = fmaf(e, bhi(v.y), a8[3]);
    a8[4] = fmaf(e, blo(v.z), a8[4]); a8[5] = fmaf(e, bhi(v.z), a8[5]);
    a8[6] = fmaf(e, blo(v.w), a8[6]); a8[7] = fmaf(e, bhi(v.w), a8[7]);
}

// ---------------------------------------------------------------------------
// MFMA GEMM (bf16x2 split, fp32-grade accuracy):
//   out[m][n] = sum_k A[m][k] * W[n][k] + bias[n]
// A,W are f32 in global, split into (hi,lo) bf16 during LDS staging.
// acc = Ah*Wh + Ah*Wl + Al*Wh  (lo*lo term ~2^-18, dropped).
// BM=BN=128, K=128 staged whole (no k-loop). 256 threads = 4 waves (2x2),
// each wave computes 64x64 via 4x4 fragments of mfma_f32_16x16x32_bf16.
// LDS: 4 x 32KB, 256B rows, XOR swizzle (byte ^= (row&7)<<4) -> 2-way reads.
// SELQKV=1: N=384 (blockIdx.y = q/k/v), scatter epilogue. SELQKV=0: N=128.
// ---------------------------------------------------------------------------
template <int SELQKV>
__global__ __launch_bounds__(256, 1) void gemm_mfma(
    const float* __restrict__ A, const float* __restrict__ Wm,
    const float* __restrict__ bias,
    float* __restrict__ outq, __hip_bfloat16* __restrict__ outk,
    __hip_bfloat16* __restrict__ outv, float* __restrict__ outp)
{
    __shared__ short Ah[128 * 128];
    __shared__ short Al[128 * 128];
    __shared__ short Bh[128 * 128];
    __shared__ short Bl[128 * 128];

    const int tid = threadIdx.x;
    const int m0 = blockIdx.x * 128;
    const int n0 = blockIdx.y * 128;

    // ---- stage A and B: f32 global -> (hi,lo) bf16 LDS, swizzled ----
#pragma unroll
    for (int it = 0; it < 16; ++it) {
        int idx = tid + it * 256;          // 0..4095 float4-chunks
        int r   = idx >> 5;                // row 0..127
        int c4  = idx & 31;                // float4 within row
        int byte = (r * 256 + c4 * 8) ^ ((r & 7) << 4);

        float4 a = *(const float4*)(A + (size_t)(m0 + r) * 128 + c4 * 4);
        short4 h, l;
        h.x = (short)f2b(a.x); l.x = (short)f2b(a.x - b2f(f2b(a.x)));
        h.y = (short)f2b(a.y); l.y = (short)f2b(a.y - b2f(f2b(a.y)));
        h.z = (short)f2b(a.z); l.z = (short)f2b(a.z - b2f(f2b(a.z)));
        h.w = (short)f2b(a.w); l.w = (short)f2b(a.w - b2f(f2b(a.w)));
        *(short4*)((char*)Ah + byte) = h;
        *(short4*)((char*)Al + byte) = l;

        float4 b = *(const float4*)(Wm + (size_t)(n0 + r) * 128 + c4 * 4);
        h.x = (short)f2b(b.x); l.x = (short)f2b(b.x - b2f(f2b(b.x)));
        h.y = (short)f2b(b.y); l.y = (short)f2b(b.y - b2f(f2b(b.y)));
        h.z = (short)f2b(b.z); l.z = (short)f2b(b.z - b2f(f2b(b.z)));
        h.w = (short)f2b(b.w); l.w = (short)f2b(b.w - b2f(f2b(b.w)));
        *(short4*)((char*)Bh + byte) = h;
        *(short4*)((char*)Bl + byte) = l;
    }
    __syncthreads();

    const int lane = tid & 63;
    const int w  = tid >> 6;
    const int wr = w >> 1, wc = w & 1;       // 2x2 waves -> 128x128
    const int fr = lane & 15;                // fragment row/col
    const int kq = (lane >> 4) << 3;         // k-offset 0,8,16,24

    f32x4 acc[4][4];
#pragma unroll
    for (int i = 0; i < 4; ++i)
#pragma unroll
        for (int j = 0; j < 4; ++j) acc[i][j] = (f32x4){0.f, 0.f, 0.f, 0.f};

#pragma unroll
    for (int ks = 0; ks < 4; ++ks) {
        int kb = (ks * 32 + kq) * 2;         // byte offset of 8-bf16 group
        short8v ah[4], al[4], bh[4], bl[4];
#pragma unroll
        for (int mi = 0; mi < 4; ++mi) {
            int row = wr * 64 + mi * 16 + fr;
            int byte = (row * 256 + kb) ^ ((row & 7) << 4);
            ah[mi] = *(const short8v*)((const char*)Ah + byte);
            al[mi] = *(const short8v*)((const char*)Al + byte);
        }
#pragma unroll
        for (int ni = 0; ni < 4; ++ni) {
            int row = wc * 64 + ni * 16 + fr;
            int byte = (row * 256 + kb) ^ ((row & 7) << 4);
            bh[ni] = *(const short8v*)((const char*)Bh + byte);
            bl[ni] = *(const short8v*)((const char*)Bl + byte);
        }
#pragma unroll
        for (int mi = 0; mi < 4; ++mi)
#pragma unroll
            for (int ni = 0; ni < 4; ++ni) {
                acc[mi][ni] = __builtin_amdgcn_mfma_f32_16x16x32_bf16(ah[mi], bh[ni], acc[mi][ni], 0, 0, 0);
                acc[mi][ni] = __builtin_amdgcn_mfma_f32_16x16x32_bf16(ah[mi], bl[ni], acc[mi][ni], 0, 0, 0);
                acc[mi][ni] = __builtin_amdgcn_mfma_f32_16x16x32_bf16(al[mi], bh[ni], acc[mi][ni], 0, 0, 0);
            }
    }

    // ---- epilogue: C/D layout col=lane&15, row=4*(lane>>4)+reg ----
    const int cl = lane & 15;
    const int rq = lane >> 4;

    if constexpr (SELQKV) {
        const int sel = blockIdx.y;          // 0=q 1=k 2=v
#pragma unroll
        for (int mi = 0; mi < 4; ++mi) {
#pragma unroll
            for (int reg = 0; reg < 4; ++reg) {
                int m = m0 + wr * 64 + mi * 16 + rq * 4 + reg;
                int b = m / 3136;
                int r = m - b * 3136;
                int y = r / 56;
                int x = r - y * 56;
#pragma unroll
                for (int ni = 0; ni < 4; ++ni) {
                    int nn = wc * 64 + ni * 16 + cl;     // 0..127 in component
                    float val = acc[mi][ni][reg] + bias[n0 + nn];
                    int h = nn >> 5, d = nn & 31;
                    size_t oi = ((size_t)((b * NH + h) * 3136) + y * 56 + x) * 32 + d;
                    if (sel == 0)      outq[oi] = val * SCALE;
                    else if (sel == 1) outk[oi] = __float2bfloat16(val);
                    else               outv[oi] = __float2bfloat16(val);
                }
            }
        }
    } else {
#pragma unroll
        for (int mi = 0; mi < 4; ++mi) {
#pragma unroll
            for (int reg = 0; reg < 4; ++reg) {
                int m = m0 + wr * 64 + mi * 16 + rq * 4 + reg;
#pragma unroll
                for (int ni = 0; ni < 4; ++ni) {
                    int nn = wc * 64 + ni * 16 + cl;
                    outp[(size_t)m * 128 + nn] = acc[mi][ni][reg] + bias[nn];
                }
            }
        }
    }
}

// ---------------------------------------------------------------------------
// Neighborhood attention (unchanged from round 1). Block = (b, head, 8x28
// pixel tile), 256 threads (224 active). k/v halo 14x34 staged as bf16 in
// LDS, zero-filled OOB (matches reference zero-padding: OOB score = rpb,
// v = 0). Single-pass softmax without max-subtraction (scores O(0.1)).
// ---------------------------------------------------------------------------
__global__ __launch_bounds__(256, 2) void natt_k(
    const float* __restrict__ qs, const __hip_bfloat16* __restrict__ kb,
    const __hip_bfloat16* __restrict__ vb, const float* __restrict__ rpb,
    float* __restrict__ attn_out)
{
    __shared__ uint4 ks[4 * 476];   // [chunk c][pix]  pix = i*34+j, halo 14x34
    __shared__ uint4 vs[4 * 476];
    __shared__ float rp[49];

    const int tid = threadIdx.x;
    const int b = blockIdx.z, h = blockIdx.y;
    const int yt = blockIdx.x >> 1, xt = blockIdx.x & 1;
    const int y0 = yt * 8, x0 = xt * 28;
    const int bh = b * NH + h;

    if (tid < 49) rp[tid] = rpb[h * 49 + tid];

    const uint4* kg = (const uint4*)kb;  // 4 uint4 per pixel (32 bf16)
    const uint4* vg = (const uint4*)vb;
    for (int idx = tid; idx < 1904; idx += 256) {
        int pix = idx >> 2, c = idx & 3;
        int i = pix / 34;
        int j = pix - i * 34;
        int y = y0 + i - PAD;
        int x = x0 + j - PAD;
        uint4 z = make_uint4(0u, 0u, 0u, 0u);
        if ((unsigned)y < 56u && (unsigned)x < 56u) {
            int g = ((bh * 3136) + y * 56 + x) * 4 + c;
            ks[c * 476 + pix] = kg[g];
            vs[c * 476 + pix] = vg[g];
        } else {
            ks[c * 476 + pix] = z;
            vs[c * 476 + pix] = z;
        }
    }
    __syncthreads();

    if (tid >= 224) return;
    int py = tid / 28;
    int px = tid - py * 28;

    float q[32];
    {
        const float4* qgp = (const float4*)(qs + ((size_t)(bh * 3136) + (y0 + py) * 56 + (x0 + px)) * 32);
#pragma unroll
        for (int c = 0; c < 8; ++c) {
            float4 t = qgp[c];
            q[4 * c + 0] = t.x; q[4 * c + 1] = t.y; q[4 * c + 2] = t.z; q[4 * c + 3] = t.w;
        }
    }

    float acc[32];
#pragma unroll
    for (int d = 0; d < 32; ++d) acc[d] = 0.f;
    float l = 0.f;

    for (int dy = 0; dy < 7; ++dy) {
        int rowbase = (py + dy) * 34 + px;
#pragma unroll
        for (int dx = 0; dx < 7; ++dx) {
            int pix = rowbase + dx;
            float s = 0.f;
#pragma unroll
            for (int c = 0; c < 4; ++c) {
                uint4 kk = ks[c * 476 + pix];
                s += dot8(&q[c * 8], kk);
            }
            s += rp[dy * 7 + dx];
            float e = __expf(s);
            l += e;
#pragma unroll
            for (int c = 0; c < 4; ++c) {
                uint4 vv = vs[c * 476 + pix];
                axpy8(&acc[c * 8], e, vv);
            }
        }
    }

    float rl = 1.0f / l;
    float* op = attn_out + ((size_t)(b * 3136) + (y0 + py) * 56 + (x0 + px)) * 128 + h * 32;
#pragma unroll
    for (int c = 0; c < 8; ++c) {
        float4 o;
        o.x = acc[4 * c + 0] * rl; o.y = acc[4 * c + 1] * rl;
        o.z = acc[4 * c + 2] * rl; o.w = acc[4 * c + 3] * rl;
        *(float4*)(op + 4 * c) = o;
    }
}

extern "C" void kernel_launch(void* const* d_in, const int* in_sizes, int n_in,
                              void* d_out, int out_size, void* d_ws, size_t ws_size,
                              hipStream_t stream)
{
    const float* x     = (const float*)d_in[0];
    const float* Wqkv  = (const float*)d_in[1];
    const float* bqkv  = (const float*)d_in[2];
    const float* rpb   = (const float*)d_in[3];
    const float* Wproj = (const float*)d_in[4];
    const float* bproj = (const float*)d_in[5];
    float* out = (float*)d_out;

    char* ws = (char*)d_ws;
    float*           qsb  = (float*)(ws + QS_OFF);
    __hip_bfloat16*  kbuf = (__hip_bfloat16*)(ws + K_OFF);
    __hip_bfloat16*  vbuf = (__hip_bfloat16*)(ws + V_OFF);
    float*           attn = (float*)(ws + AT_OFF);

    // 1) QKV projection (MFMA): 196 m-tiles x 3 n-tiles (q / k / v)
    gemm_mfma<1><<<dim3(196, 3), 256, 0, stream>>>(x, Wqkv, bqkv, qsb, kbuf, vbuf, nullptr);

    // 2) neighborhood attention: 14 tiles x 4 heads x 8 batch
    natt_k<<<dim3(14, NH, 8), 256, 0, stream>>>(qsb, kbuf, vbuf, rpb, attn);

    // 3) output projection (MFMA)
    gemm_mfma<0><<<dim3(196, 1), 256, 0, stream>>>(attn, Wproj, bproj, nullptr, nullptr, nullptr, out);
}